// Round 2
// baseline (99.972 us; speedup 1.0000x reference)
//
#include <hip/hip_runtime.h>
#include <hip/hip_bf16.h>

// feature [B=128, E=64, D=128] fp32 -> N = 8192 rows of dim 128.
// loss = mean_r( log(den_r) - log(pos_r) ),
//   den_r = sum_c exp(10*<f_r,f_c>), pos_r = sum over c in r's 64-row block.
#define N_ROWS 8192
#define DIM    128
#define TILE   128
#define CPG    8     // col tiles per block
#define EXPTEN 22026.465794806718f  // exp(10.0)
// Xb = normalize(f) * SCALE, SCALE^2 = 10*log2(e); then exp2(dot) = exp(10*<f,f>)
#define SCALE  3.7982826f

typedef __attribute__((ext_vector_type(8))) short short8;   // 8 bf16 = 4 VGPRs
typedef __attribute__((ext_vector_type(4))) float floatx4;  // MFMA C/D

#if __has_builtin(__builtin_amdgcn_exp2f)
#define EXP2F(x) __builtin_amdgcn_exp2f(x)
#else
#define EXP2F(x) __expf((x) * 0.6931471805599453f)
#endif

// ---- Kernel 1: L2-normalize rows, scale, cast to bf16; zero pos/den ----
__global__ void norm_kernel(const float* __restrict__ F, __hip_bfloat16* __restrict__ Xb,
                            float* __restrict__ pos, float* __restrict__ den) {
    int lane = threadIdx.x & 63;
    int wave = threadIdx.x >> 6;
    int row  = blockIdx.x * 4 + wave;           // 2048 blocks x 4 waves = 8192 rows
    const float2 v = *(const float2*)(F + (size_t)row * DIM + lane * 2);
    float ss = v.x * v.x + v.y * v.y;
    #pragma unroll
    for (int m = 1; m < 64; m <<= 1) ss += __shfl_xor(ss, m);
    float inv = rsqrtf(ss) * SCALE;
    __hip_bfloat162 o;
    o.x = __float2bfloat16(v.x * inv);
    o.y = __float2bfloat16(v.y * inv);
    *((__hip_bfloat162*)(Xb + (size_t)row * DIM) + lane) = o;
    if (lane == 0) { pos[row] = 0.f; den[row] = 0.f; }
}

// ---- Kernel 2: LDS-free fused gram + exp + row sums ----
// Block (rb, cg): rows [rb*128, +128) x col tiles ct = cg*8..cg*8+7 (128 cols each).
// 4 waves in 2x2 (wm, wn); wave owns 64x64 per tile via 4x4 MFMA 16x16x32.
// A fragments register-resident across all 8 tiles; B fragments streamed from L2
// (Xb is 2 MB -> resident in every XCD L2). No LDS, no __syncthreads.
__global__ __launch_bounds__(256, 2) void gram_kernel(
        const __hip_bfloat16* __restrict__ Xb,
        float* __restrict__ pos, float* __restrict__ den) {
    const int tid  = threadIdx.x;
    const int rb   = blockIdx.x;      // 0..63
    const int cg   = blockIdx.y;      // 0..7
    const int lane = tid & 63;
    const int wave = tid >> 6;
    const int wm   = wave >> 1, wn = wave & 1;
    const int quad = lane >> 4;       // 0..3
    const int l15  = lane & 15;       // 0..15

    // A fragments: lane needs rows rb*128+wm*64+mi*16+l15, elems ko*32+quad*8..+8.
    // One 16B load per (mi,ko): 16 rows x 64B chunk = 16 full cache lines, coalesced.
    short8 af[4][4];
    {
        const __hip_bfloat16* Ab = Xb + ((size_t)(rb * TILE + wm * 64 + l15)) * DIM + quad * 8;
        #pragma unroll
        for (int mi = 0; mi < 4; ++mi)
            #pragma unroll
            for (int ko = 0; ko < 4; ++ko)
                af[mi][ko] = *(const short8*)(Ab + mi * 16 * DIM + ko * 32);
    }

    float dp[4][4];
    #pragma unroll
    for (int a = 0; a < 4; ++a)
        #pragma unroll
        for (int b = 0; b < 4; ++b) dp[a][b] = 0.f;

    floatx4 acc[4][4];
    short8 bfr[4][4];

    // epilogue over acc for col-tile ct: exp2, accumulate den partials, emit pos.
    auto epilogue = [&](int ct) {
        const bool pos_tile = (ct == rb) && (wm == wn);
        #pragma unroll
        for (int mi = 0; mi < 4; ++mi)
            #pragma unroll
            for (int rg = 0; rg < 4; ++rg) {
                float dadd = 0.f;
                #pragma unroll
                for (int ni = 0; ni < 4; ++ni)
                    dadd += EXP2F(acc[mi][ni][rg]);
                if (pos_tile) {
                    // diagonal element: ni==mi fragment, col l15 == row quad*4+rg;
                    // replace bf16-noisy exp(10*||x||^2) with exact exp(10).
                    if (l15 == quad * 4 + rg)
                        dadd += EXPTEN - EXP2F(acc[mi][mi][rg]);
                    float p = dadd;
                    #pragma unroll
                    for (int m = 1; m < 16; m <<= 1) p += __shfl_xor(p, m);
                    if (l15 == 0)
                        atomicAdd(&pos[rb * TILE + wm * 64 + mi * 16 + quad * 4 + rg], p);
                }
                dp[mi][rg] += dadd;
            }
    };

    auto load_b = [&](int ct) {
        const __hip_bfloat16* Bb = Xb + ((size_t)(ct * TILE + wn * 64 + l15)) * DIM + quad * 8;
        #pragma unroll
        for (int ni = 0; ni < 4; ++ni)
            #pragma unroll
            for (int ko = 0; ko < 4; ++ko)
                bfr[ni][ko] = *(const short8*)(Bb + ni * 16 * DIM + ko * 32);
    };

    auto do_mfma = [&]() {
        #pragma unroll
        for (int mi = 0; mi < 4; ++mi)
            #pragma unroll
            for (int ni = 0; ni < 4; ++ni) acc[mi][ni] = (floatx4)0.0f;
        #pragma unroll
        for (int ko = 0; ko < 4; ++ko)
            #pragma unroll
            for (int mi = 0; mi < 4; ++mi)
                #pragma unroll
                for (int ni = 0; ni < 4; ++ni)
                    acc[mi][ni] = __builtin_amdgcn_mfma_f32_16x16x32_bf16(
                        af[mi][ko], bfr[ni][ko], acc[mi][ni], 0, 0, 0);
    };

    // Software pipeline: loads(t) issued -> epilogue(t-1) fills L2 latency -> MFMA(t).
    load_b(cg * CPG);
    do_mfma();
    #pragma unroll 1
    for (int t = 1; t < CPG; ++t) {
        load_b(cg * CPG + t);
        epilogue(cg * CPG + t - 1);
        do_mfma();
    }
    epilogue(cg * CPG + CPG - 1);

    // den: reduce across the 16 lanes of each quad group, one atomic per row.
    #pragma unroll
    for (int mi = 0; mi < 4; ++mi)
        #pragma unroll
        for (int rg = 0; rg < 4; ++rg) {
            float d = dp[mi][rg];
            #pragma unroll
            for (int m = 1; m < 16; m <<= 1) d += __shfl_xor(d, m);
            if (l15 == 0)
                atomicAdd(&den[rb * TILE + wm * 64 + mi * 16 + quad * 4 + rg], d);
        }
}

// ---- Kernel 3: loss = mean(log(den/pos)) ----
__global__ void loss_kernel(const float* __restrict__ pos, const float* __restrict__ den,
                            float* __restrict__ out) {
    __shared__ float red[4];
    float acc = 0.f;
    for (int i = threadIdx.x; i < N_ROWS / 4; i += 256) {
        float4 d = ((const float4*)den)[i];
        float4 p = ((const float4*)pos)[i];
        acc += __logf(d.x / p.x) + __logf(d.y / p.y) +
               __logf(d.z / p.z) + __logf(d.w / p.w);
    }
    #pragma unroll
    for (int m = 1; m < 64; m <<= 1) acc += __shfl_xor(acc, m);
    int lane = threadIdx.x & 63, w = threadIdx.x >> 6;
    if (lane == 0) red[w] = acc;
    __syncthreads();
    if (threadIdx.x == 0)
        out[0] = (red[0] + red[1] + red[2] + red[3]) * (1.0f / (float)N_ROWS);
}

extern "C" void kernel_launch(void* const* d_in, const int* in_sizes, int n_in,
                              void* d_out, int out_size, void* d_ws, size_t ws_size,
                              hipStream_t stream) {
    const float* feature = (const float*)d_in[0];
    // ws layout: pos[8192] f32 | den[8192] f32 | Xb[8192*128] bf16
    float* pos = (float*)d_ws;
    float* den = pos + N_ROWS;
    __hip_bfloat16* Xb = (__hip_bfloat16*)(den + N_ROWS);

    norm_kernel<<<N_ROWS / 4, 256, 0, stream>>>(feature, Xb, pos, den);
    gram_kernel<<<dim3(64, 8), 256, 0, stream>>>(Xb, pos, den);
    loss_kernel<<<1, 256, 0, stream>>>(pos, den, (float*)d_out);
}

// Round 3
// 87.686 us; speedup vs baseline: 1.1401x; 1.1401x over previous
//
#include <hip/hip_runtime.h>
#include <hip/hip_bf16.h>

// feature [B=128, E=64, D=128] fp32 -> N = 8192 rows of dim 128.
// loss = mean_r( log(den_r) - log(pos_r) ),
//   den_r = sum_c exp(10*<f_r,f_c>), pos_r = sum over c in r's 64-row block.
#define N_ROWS 8192
#define DIM    128
#define TILE   128
#define CPG    8     // col tiles per block
#define EXPTEN 22026.465794806718f  // exp(10.0)
// Xb = normalize(f) * SCALE, SCALE^2 = 10*log2(e); then exp2(dot) = exp(10*<f,f>)
#define SCALE  3.7982826f

typedef __attribute__((ext_vector_type(8))) short short8;   // 8 bf16 = 4 VGPRs
typedef __attribute__((ext_vector_type(4))) float floatx4;  // MFMA C/D

#define EXP2F(x) __builtin_amdgcn_exp2f(x)

// async global->LDS DMA, 16B per lane; LDS dest = uniform base + lane*16
#define GLOAD_LDS(g, l)                                                        \
    __builtin_amdgcn_global_load_lds(                                          \
        (const __attribute__((address_space(1))) void*)(g),                    \
        (__attribute__((address_space(3))) void*)(l), 16, 0, 0)

// ---- Kernel 1: L2-normalize rows, scale, cast to bf16; zero pos/den ----
__global__ void norm_kernel(const float* __restrict__ F, __hip_bfloat16* __restrict__ Xb,
                            float* __restrict__ pos, float* __restrict__ den) {
    int lane = threadIdx.x & 63;
    int wave = threadIdx.x >> 6;
    int row  = blockIdx.x * 4 + wave;           // 2048 blocks x 4 waves = 8192 rows
    const float2 v = *(const float2*)(F + (size_t)row * DIM + lane * 2);
    float ss = v.x * v.x + v.y * v.y;
    #pragma unroll
    for (int m = 1; m < 64; m <<= 1) ss += __shfl_xor(ss, m);
    float inv = rsqrtf(ss) * SCALE;
    __hip_bfloat162 o;
    o.x = __float2bfloat16(v.x * inv);
    o.y = __float2bfloat16(v.y * inv);
    *((__hip_bfloat162*)(Xb + (size_t)row * DIM) + lane) = o;
    if (lane == 0) { pos[row] = 0.f; den[row] = 0.f; }
}

// ---- Kernel 2: fused gram + exp + row sums ----
// Block (rb, cg): rows [rb*128,+128) x col tiles ct = cg*8..cg*8+7.
// 4 waves 2x2 (wm,wn), each wave 64x64 per tile via 4x4 MFMA 16x16x32 bf16.
// A fragments register-resident (loaded once). B tiles staged to LDS with
// async global_load_lds (no VGPR round-trip), double-buffered: stage(t+1) is
// issued a full compute-tile (~1000 cyc) before the barrier that drains it.
// XOR swizzle (chunk ^ row&15) folded into the *global* source address so the
// fragment ds_read_b128s are bank-conflict-free despite the forced contiguous
// LDS layout.
__global__ __launch_bounds__(256, 2) void gram_kernel(
        const __hip_bfloat16* __restrict__ Xb,
        float* __restrict__ pos, float* __restrict__ den) {
    __shared__ __hip_bfloat16 Bs[2][TILE * DIM];   // 2 x 32 KB
    const int tid  = threadIdx.x;
    const int rb   = blockIdx.x;      // 0..63
    const int cg   = blockIdx.y;      // 0..7
    const int lane = tid & 63;
    const int wave = tid >> 6;
    const int wm   = wave >> 1, wn = wave & 1;
    const int quad = lane >> 4;       // 0..3
    const int l15  = lane & 15;       // 0..15

    // A fragments: rows rb*128+wm*64+mi*16+l15, elems ko*32+quad*8 (one-time cost).
    short8 af[4][4];
    {
        const __hip_bfloat16* Ab = Xb + ((size_t)(rb * TILE + wm * 64 + l15)) * DIM + quad * 8;
        #pragma unroll
        for (int mi = 0; mi < 4; ++mi)
            #pragma unroll
            for (int ko = 0; ko < 4; ++ko)
                af[mi][ko] = *(const short8*)(Ab + mi * 16 * DIM + ko * 32);
    }

    float dp[4][4];
    #pragma unroll
    for (int a = 0; a < 4; ++a)
        #pragma unroll
        for (int b = 0; b < 4; ++b) dp[a][b] = 0.f;

    // Stage B tile ct into Bs[buf]: 2048 16B-chunks, 8 issues/wave.
    // LDS chunk j holds global chunk (j&15) ^ (row&15) of row j>>4.
    auto stage = [&](int ct, int buf) {
        #pragma unroll
        for (int i = 0; i < 8; ++i) {
            int chunk = (i * 4 + wave) * 64 + lane;
            int r  = chunk >> 4;
            int cs = (chunk & 15) ^ (r & 15);
            const __hip_bfloat16* gp = Xb + ((size_t)(ct * TILE + r)) * DIM + cs * 8;
            char* lp = (char*)&Bs[buf][0] + (i * 4 + wave) * 1024;  // wave-uniform
            GLOAD_LDS(gp, lp);
        }
    };

    auto compute = [&](int ct, int buf) {
        floatx4 acc[4][4];
        #pragma unroll
        for (int mi = 0; mi < 4; ++mi)
            #pragma unroll
            for (int ni = 0; ni < 4; ++ni) acc[mi][ni] = (floatx4)0.0f;

        const char* Bb = (const char*)&Bs[buf][0];
        #pragma unroll
        for (int ko = 0; ko < 4; ++ko) {
            short8 bf[4];
            #pragma unroll
            for (int ni = 0; ni < 4; ++ni) {
                int r  = wn * 64 + ni * 16 + l15;
                int ch = (ko * 4 + quad) ^ l15;   // undo the staging swizzle
                bf[ni] = *(const short8*)(Bb + r * 256 + ch * 16);
            }
            #pragma unroll
            for (int mi = 0; mi < 4; ++mi)
                #pragma unroll
                for (int ni = 0; ni < 4; ++ni)
                    acc[mi][ni] = __builtin_amdgcn_mfma_f32_16x16x32_bf16(
                        af[mi][ko], bf[ni], acc[mi][ni], 0, 0, 0);
        }

        const bool pos_tile = (ct == rb) && (wm == wn);
        #pragma unroll
        for (int mi = 0; mi < 4; ++mi)
            #pragma unroll
            for (int rg = 0; rg < 4; ++rg) {
                float dadd = 0.f;
                #pragma unroll
                for (int ni = 0; ni < 4; ++ni)
                    dadd += EXP2F(acc[mi][ni][rg]);
                if (pos_tile) {
                    // diagonal: replace bf16-noisy exp(10*||x||^2) with exact exp(10)
                    if (l15 == quad * 4 + rg)
                        dadd += EXPTEN - EXP2F(acc[mi][mi][rg]);
                    float p = dadd;
                    #pragma unroll
                    for (int m = 1; m < 16; m <<= 1) p += __shfl_xor(p, m);
                    if (l15 == 0)
                        atomicAdd(&pos[rb * TILE + wm * 64 + mi * 16 + quad * 4 + rg], p);
                }
                dp[mi][rg] += dadd;
            }
    };

    stage(cg * CPG, 0);
    __syncthreads();                       // drains stage(0) + A loads
    #pragma unroll 1
    for (int t = 0; t < CPG - 1; ++t) {
        stage(cg * CPG + t + 1, (t + 1) & 1);  // async, drains at loop-end barrier
        compute(cg * CPG + t, t & 1);          // ~1000 cyc covers the staging latency
        __syncthreads();
    }
    compute(cg * CPG + CPG - 1, (CPG - 1) & 1);

    // den: reduce across the 16 lanes of each quad group, one atomic per row.
    #pragma unroll
    for (int mi = 0; mi < 4; ++mi)
        #pragma unroll
        for (int rg = 0; rg < 4; ++rg) {
            float d = dp[mi][rg];
            #pragma unroll
            for (int m = 1; m < 16; m <<= 1) d += __shfl_xor(d, m);
            if (l15 == 0)
                atomicAdd(&den[rb * TILE + wm * 64 + mi * 16 + quad * 4 + rg], d);
        }
}

// ---- Kernel 3: loss = mean(log(den/pos)) ----
__global__ void loss_kernel(const float* __restrict__ pos, const float* __restrict__ den,
                            float* __restrict__ out) {
    __shared__ float red[4];
    float acc = 0.f;
    for (int i = threadIdx.x; i < N_ROWS / 4; i += 256) {
        float4 d = ((const float4*)den)[i];
        float4 p = ((const float4*)pos)[i];
        acc += __logf(d.x / p.x) + __logf(d.y / p.y) +
               __logf(d.z / p.z) + __logf(d.w / p.w);
    }
    #pragma unroll
    for (int m = 1; m < 64; m <<= 1) acc += __shfl_xor(acc, m);
    int lane = threadIdx.x & 63, w = threadIdx.x >> 6;
    if (lane == 0) red[w] = acc;
    __syncthreads();
    if (threadIdx.x == 0)
        out[0] = (red[0] + red[1] + red[2] + red[3]) * (1.0f / (float)N_ROWS);
}

extern "C" void kernel_launch(void* const* d_in, const int* in_sizes, int n_in,
                              void* d_out, int out_size, void* d_ws, size_t ws_size,
                              hipStream_t stream) {
    const float* feature = (const float*)d_in[0];
    // ws layout: pos[8192] f32 | den[8192] f32 | Xb[8192*128] bf16
    float* pos = (float*)d_ws;
    float* den = pos + N_ROWS;
    __hip_bfloat16* Xb = (__hip_bfloat16*)(den + N_ROWS);

    norm_kernel<<<N_ROWS / 4, 256, 0, stream>>>(feature, Xb, pos, den);
    gram_kernel<<<dim3(64, 8), 256, 0, stream>>>(Xb, pos, den);
    loss_kernel<<<1, 256, 0, stream>>>(pos, den, (float*)d_out);
}